// Round 1
// baseline (570.556 us; speedup 1.0000x reference)
//
#include <hip/hip_runtime.h>

#define D 2048
#define KPAD 160
#define PSTR 168
#define XSTR 2056
#define MTILE 16
#define THREADS 512

typedef __attribute__((ext_vector_type(8))) short bf16x8;
typedef __attribute__((ext_vector_type(4))) float f32x4;

__device__ inline unsigned short f2bf(float f) {
  unsigned int u = __float_as_uint(f);
  u += 0x7fffu + ((u >> 16) & 1u);   // round-to-nearest-even
  return (unsigned short)(u >> 16);
}
__device__ inline float bf2f(unsigned short h) {
  return __uint_as_float(((unsigned int)h) << 16);
}

// ---- prep: pack Wp|Wv -> Wpv_t[32][2048] bf16 (n-major, k contiguous) ----
__global__ __launch_bounds__(256) void prep_wpv(const float* __restrict__ Wp,
                                                const float* __restrict__ Wv,
                                                unsigned short* __restrict__ Wpvt) {
  int idx = blockIdx.x * 256 + threadIdx.x;   // 32*2048 elements
  int n = idx >> 11, k = idx & 2047;
  float v = 0.f;
  if (n < 12) v = Wp[k * 12 + n];
  else if (n < 24) v = Wv[k * 12 + (n - 12)];
  Wpvt[idx] = f2bf(v);
}

// ---- prep: Wi[144][2048] -> Wi_t[2048][160] bf16 (n-major, k contiguous, K padded) ----
__global__ __launch_bounds__(256) void prep_wi(const float* __restrict__ Wi,
                                               unsigned short* __restrict__ Wit) {
  int idx = blockIdx.x * 256 + threadIdx.x;   // 2048*160 elements
  int n = idx / KPAD, k = idx - n * KPAD;
  float v = (k < 144) ? Wi[k * 2048 + n] : 0.f;
  Wit[idx] = f2bf(v);
}

// ---- fused: pos/vel -> outer -> @Wi -> residual -> LayerNorm ----
__global__ __launch_bounds__(THREADS) void gil_fused(
    const float* __restrict__ x, const float* __restrict__ bp,
    const float* __restrict__ bv, const float* __restrict__ bi,
    const float* __restrict__ gamma, const float* __restrict__ beta,
    const unsigned short* __restrict__ Wpvt, const unsigned short* __restrict__ Wit,
    float* __restrict__ out) {
  __shared__ unsigned short xt[MTILE][XSTR];    // x tile, bf16  (65792 B)
  __shared__ unsigned short sP[MTILE][PSTR];    // P = pos (x) vel, bf16, K-padded
  __shared__ float sred[4][MTILE][32];          // phase-1 K-split partials
  __shared__ float spv[MTILE][32];              // pos|vel after reduce+bias
  __shared__ float spart[8][MTILE][2];          // per-wave LN partials
  __shared__ float sstat[MTILE][2];             // mu, rsigma

  const int t = threadIdx.x;
  const int rowbase = blockIdx.x * MTILE;

  // ---- phase 0: stage x tile -> LDS bf16 (coalesced float4 reads) ----
  {
    int r = t >> 5, u = t & 31;
    const float4* xr = (const float4*)(x + (size_t)(rowbase + r) * D);
#pragma unroll
    for (int j = 0; j < 16; ++j) {
      float4 v = xr[u + 32 * j];
      ushort4 p;
      p.x = f2bf(v.x); p.y = f2bf(v.y); p.z = f2bf(v.z); p.w = f2bf(v.w);
      *(ushort4*)&xt[r][4 * (u + 32 * j)] = p;
    }
  }
  __syncthreads();

  const int wave = t >> 6, lane = t & 63;
  const int lm = lane & 15, quad = lane >> 4;

  // ---- phase 1: pos|vel = x @ Wpv  (2 n-tiles x 4 K-slices across 8 waves) ----
  {
    int nt = wave & 1, ks = wave >> 1;
    f32x4 acc = {0.f, 0.f, 0.f, 0.f};
    const unsigned short* bptr = Wpvt + (nt * 16 + lm) * D;
#pragma unroll
    for (int kk = 0; kk < 16; ++kk) {
      int k0 = ks * 512 + kk * 32 + quad * 8;
      bf16x8 a = *(const bf16x8*)&xt[lm][k0];
      bf16x8 b = *(const bf16x8*)(bptr + k0);
      acc = __builtin_amdgcn_mfma_f32_16x16x32_bf16(a, b, acc, 0, 0, 0);
    }
#pragma unroll
    for (int rg = 0; rg < 4; ++rg)
      sred[ks][quad * 4 + rg][nt * 16 + lm] = acc[rg];
  }
  __syncthreads();

  // ---- phase 1b: K-reduce + bias; then P[m][i*12+j] = pos_i * vel_j (bf16) ----
  {
    int m = t >> 5, n = t & 31;
    float pv = sred[0][m][n] + sred[1][m][n] + sred[2][m][n] + sred[3][m][n];
    if (n < 12) pv += bp[n];
    else if (n < 24) pv += bv[n - 12];
    spv[m][n] = pv;
  }
  __syncthreads();
  {
    int m = t >> 5, n = t & 31;
#pragma unroll
    for (int k = n; k < KPAD; k += 32) {
      float v = 0.f;
      if (k < 144) {
        int i = k / 12, j = k - i * 12;
        v = spv[m][i] * spv[m][12 + j];
      }
      sP[m][k] = f2bf(v);
    }
  }
  __syncthreads();

  // ---- phase 2: inter = P @ Wi  (each wave: 256 cols = 16 n-tiles, K=160) ----
  f32x4 accv[16];
  {
    bf16x8 af[5];
#pragma unroll
    for (int kc = 0; kc < 5; ++kc)
      af[kc] = *(const bf16x8*)&sP[lm][kc * 32 + quad * 8];
#pragma unroll
    for (int nt = 0; nt < 16; ++nt) {
      int n = wave * 256 + nt * 16 + lm;
      const unsigned short* wb = Wit + n * KPAD;
      f32x4 acc = {0.f, 0.f, 0.f, 0.f};
#pragma unroll
      for (int kc = 0; kc < 5; ++kc) {
        bf16x8 b = *(const bf16x8*)(wb + kc * 32 + quad * 8);
        acc = __builtin_amdgcn_mfma_f32_16x16x32_bf16(af[kc], b, acc, 0, 0, 0);
      }
      accv[nt] = acc;
    }
  }

  // ---- phase 3a: y = x + inter + bi; LN stats ----
  float s[4] = {0.f, 0.f, 0.f, 0.f}, ss[4] = {0.f, 0.f, 0.f, 0.f};
#pragma unroll
  for (int nt = 0; nt < 16; ++nt) {
    int c = wave * 256 + nt * 16 + lm;
    float bic = bi[c];
#pragma unroll
    for (int rg = 0; rg < 4; ++rg) {
      int row = quad * 4 + rg;
      float y = accv[nt][rg] + bic + bf2f(xt[row][c]);
      accv[nt][rg] = y;
      s[rg] += y;
      ss[rg] += y * y;
    }
  }
#pragma unroll
  for (int off = 1; off < 16; off <<= 1) {
#pragma unroll
    for (int rg = 0; rg < 4; ++rg) {
      s[rg] += __shfl_xor(s[rg], off);
      ss[rg] += __shfl_xor(ss[rg], off);
    }
  }
  if (lm == 0) {
#pragma unroll
    for (int rg = 0; rg < 4; ++rg) {
      spart[wave][quad * 4 + rg][0] = s[rg];
      spart[wave][quad * 4 + rg][1] = ss[rg];
    }
  }
  __syncthreads();
  if (t < MTILE) {
    float su = 0.f, sq = 0.f;
#pragma unroll
    for (int w = 0; w < 8; ++w) { su += spart[w][t][0]; sq += spart[w][t][1]; }
    float mu = su * (1.f / D);
    float var = sq * (1.f / D) - mu * mu;
    sstat[t][0] = mu;
    sstat[t][1] = rsqrtf(var + 1e-5f);
  }
  __syncthreads();

  // ---- phase 3b: normalize + store ----
  float mu[4], rs[4];
#pragma unroll
  for (int rg = 0; rg < 4; ++rg) {
    mu[rg] = sstat[quad * 4 + rg][0];
    rs[rg] = sstat[quad * 4 + rg][1];
  }
#pragma unroll
  for (int nt = 0; nt < 16; ++nt) {
    int c = wave * 256 + nt * 16 + lm;
    float g = gamma[c], be = beta[c];
#pragma unroll
    for (int rg = 0; rg < 4; ++rg) {
      int row = quad * 4 + rg;
      out[(size_t)(rowbase + row) * D + c] = (accv[nt][rg] - mu[rg]) * rs[rg] * g + be;
    }
  }
}

extern "C" void kernel_launch(void* const* d_in, const int* in_sizes, int n_in,
                              void* d_out, int out_size, void* d_ws, size_t ws_size,
                              hipStream_t stream) {
  const float* x     = (const float*)d_in[0];
  const float* Wp    = (const float*)d_in[1];
  const float* bp    = (const float*)d_in[2];
  const float* Wv    = (const float*)d_in[3];
  const float* bv    = (const float*)d_in[4];
  const float* Wi    = (const float*)d_in[5];
  const float* bi    = (const float*)d_in[6];
  const float* gamma = (const float*)d_in[7];
  const float* beta  = (const float*)d_in[8];
  float* out = (float*)d_out;

  unsigned short* Wpvt = (unsigned short*)d_ws;               // 32*2048 bf16
  unsigned short* Wit  = Wpvt + 32 * 2048;                    // 2048*160 bf16

  prep_wpv<<<(32 * 2048) / 256, 256, 0, stream>>>(Wp, Wv, Wpvt);
  prep_wi<<<(2048 * KPAD) / 256, 256, 0, stream>>>(Wi, Wit);

  int rows = in_sizes[0] / D;                                  // 32768
  gil_fused<<<rows / MTILE, THREADS, 0, stream>>>(x, bp, bv, bi, gamma, beta,
                                                  Wpvt, Wit, out);
}

// Round 2
// 555.008 us; speedup vs baseline: 1.0280x; 1.0280x over previous
//
#include <hip/hip_runtime.h>

#define D 2048
#define KPAD 160
#define PSTR 168
#define XSTR 2056
#define MTILE 16
#define THREADS 512

typedef __attribute__((ext_vector_type(8))) short bf16x8;
typedef __attribute__((ext_vector_type(4))) float f32x4;

__device__ inline unsigned short f2bf(float f) {
  unsigned int u = __float_as_uint(f);
  u += 0x7fffu + ((u >> 16) & 1u);   // round-to-nearest-even
  return (unsigned short)(u >> 16);
}
__device__ inline float bf2f(unsigned short h) {
  return __uint_as_float(((unsigned int)h) << 16);
}

// ---- prep: pack Wp|Wv -> Wpv_t[32][2048] bf16 (n-major, k contiguous) ----
__global__ __launch_bounds__(256) void prep_wpv(const float* __restrict__ Wp,
                                                const float* __restrict__ Wv,
                                                unsigned short* __restrict__ Wpvt) {
  int idx = blockIdx.x * 256 + threadIdx.x;   // 32*2048 elements
  int n = idx >> 11, k = idx & 2047;
  float v = 0.f;
  if (n < 12) v = Wp[k * 12 + n];
  else if (n < 24) v = Wv[k * 12 + (n - 12)];
  Wpvt[idx] = f2bf(v);
}

// ---- prep: Wi[144][2048] -> Wi_t[2048][160] bf16 (n-major, k contiguous, K padded) ----
__global__ __launch_bounds__(256) void prep_wi(const float* __restrict__ Wi,
                                               unsigned short* __restrict__ Wit) {
  int idx = blockIdx.x * 256 + threadIdx.x;   // 2048*160 elements
  int n = idx / KPAD, k = idx - n * KPAD;
  float v = (k < 144) ? Wi[k * 2048 + n] : 0.f;
  Wit[idx] = f2bf(v);
}

// ---- fused: pos/vel -> outer -> @Wi -> residual -> LayerNorm ----
// LDS budget: xt 65792 + sP 5376 + union 8192 = 79360 B <= 81920 -> 2 blocks/CU.
__global__ __launch_bounds__(THREADS, 4) void gil_fused(
    const float* __restrict__ x, const float* __restrict__ bp,
    const float* __restrict__ bv, const float* __restrict__ bi,
    const float* __restrict__ gamma, const float* __restrict__ beta,
    const unsigned short* __restrict__ Wpvt, const unsigned short* __restrict__ Wit,
    float* __restrict__ out) {
  __shared__ unsigned short xt[MTILE][XSTR];    // x tile, bf16 (65792 B)
  __shared__ unsigned short sP[MTILE][PSTR];    // P = pos (x) vel, bf16, K-padded (5376 B)
  // time-multiplexed scratch: sred (phase 1) vs spart/sstat (phase 3)
  __shared__ __align__(16) unsigned char ured[8192];
  float (*sred)[MTILE][32] = (float (*)[MTILE][32])ured;      // [4][16][32]
  float (*spart)[MTILE][2] = (float (*)[MTILE][2])ured;       // [8][16][2]
  float (*sstat)[2]        = (float (*)[2])(ured + 4096);     // [16][2]

  const int t = threadIdx.x;
  const int rowbase = blockIdx.x * MTILE;

  // ---- phase 0: stage x tile -> LDS bf16 (coalesced float4 reads) ----
  {
    int r = t >> 5, u = t & 31;
    const float4* xr = (const float4*)(x + (size_t)(rowbase + r) * D);
#pragma unroll
    for (int j = 0; j < 16; ++j) {
      float4 v = xr[u + 32 * j];
      ushort4 p;
      p.x = f2bf(v.x); p.y = f2bf(v.y); p.z = f2bf(v.z); p.w = f2bf(v.w);
      *(ushort4*)&xt[r][4 * (u + 32 * j)] = p;
    }
  }
  __syncthreads();

  const int wave = t >> 6, lane = t & 63;
  const int lm = lane & 15, quad = lane >> 4;

  // ---- phase 1: pos|vel = x @ Wpv  (2 n-tiles x 4 K-slices across 8 waves) ----
  {
    int nt = wave & 1, ks = wave >> 1;
    f32x4 acc = {0.f, 0.f, 0.f, 0.f};
    const unsigned short* bptr = Wpvt + (nt * 16 + lm) * D;
#pragma unroll
    for (int kk = 0; kk < 16; ++kk) {
      int k0 = ks * 512 + kk * 32 + quad * 8;
      bf16x8 a = *(const bf16x8*)&xt[lm][k0];
      bf16x8 b = *(const bf16x8*)(bptr + k0);
      acc = __builtin_amdgcn_mfma_f32_16x16x32_bf16(a, b, acc, 0, 0, 0);
    }
#pragma unroll
    for (int rg = 0; rg < 4; ++rg)
      sred[ks][quad * 4 + rg][nt * 16 + lm] = acc[rg];
  }
  __syncthreads();

  // ---- phase 1b: K-reduce + bias (per-thread), outer product via shuffles ----
  {
    int m = t >> 5, n = t & 31;   // within a wave: lanes 0-31 row m0, 32-63 row m0+1
    float pv = sred[0][m][n] + sred[1][m][n] + sred[2][m][n] + sred[3][m][n];
    if (n < 12) pv += bp[n];
    else if (n < 24) pv += bv[n - 12];
    // P[m][i*12+j] = pos_i * vel_j, bf16, zero-padded to KPAD
#pragma unroll
    for (int kk = 0; kk < 5; ++kk) {
      int k = n + 32 * kk;
      int i = k / 12, j = k - i * 12;
      float a = __shfl(pv, i, 32);
      float b = __shfl(pv, 12 + j, 32);
      sP[m][k] = f2bf((k < 144) ? a * b : 0.f);
    }
  }
  __syncthreads();

  // ---- phase 2: inter = P @ Wi  (each wave: 256 cols = 16 n-tiles, K=160) ----
  f32x4 accv[16];
  {
    bf16x8 af[5];
#pragma unroll
    for (int kc = 0; kc < 5; ++kc)
      af[kc] = *(const bf16x8*)&sP[lm][kc * 32 + quad * 8];
#pragma unroll
    for (int nt = 0; nt < 16; ++nt) {
      int n = wave * 256 + nt * 16 + lm;
      const unsigned short* wb = Wit + n * KPAD;
      f32x4 acc = {0.f, 0.f, 0.f, 0.f};
#pragma unroll
      for (int kc = 0; kc < 5; ++kc) {
        bf16x8 b = *(const bf16x8*)(wb + kc * 32 + quad * 8);
        acc = __builtin_amdgcn_mfma_f32_16x16x32_bf16(af[kc], b, acc, 0, 0, 0);
      }
      accv[nt] = acc;
    }
  }

  // ---- phase 3a: y = x + inter + bi; LN stats ----
  float s[4] = {0.f, 0.f, 0.f, 0.f}, ss[4] = {0.f, 0.f, 0.f, 0.f};
#pragma unroll
  for (int nt = 0; nt < 16; ++nt) {
    int c = wave * 256 + nt * 16 + lm;
    float bic = bi[c];
#pragma unroll
    for (int rg = 0; rg < 4; ++rg) {
      int row = quad * 4 + rg;
      float y = accv[nt][rg] + bic + bf2f(xt[row][c]);
      accv[nt][rg] = y;
      s[rg] += y;
      ss[rg] += y * y;
    }
  }
#pragma unroll
  for (int off = 1; off < 16; off <<= 1) {
#pragma unroll
    for (int rg = 0; rg < 4; ++rg) {
      s[rg] += __shfl_xor(s[rg], off);
      ss[rg] += __shfl_xor(ss[rg], off);
    }
  }
  if (lm == 0) {
#pragma unroll
    for (int rg = 0; rg < 4; ++rg) {
      spart[wave][quad * 4 + rg][0] = s[rg];
      spart[wave][quad * 4 + rg][1] = ss[rg];
    }
  }
  __syncthreads();
  if (t < MTILE) {
    float su = 0.f, sq = 0.f;
#pragma unroll
    for (int w = 0; w < 8; ++w) { su += spart[w][t][0]; sq += spart[w][t][1]; }
    float mu = su * (1.f / D);
    float var = sq * (1.f / D) - mu * mu;
    sstat[t][0] = mu;
    sstat[t][1] = rsqrtf(var + 1e-5f);
  }
  __syncthreads();

  // ---- phase 3b: normalize + store ----
  float mu[4], rs[4];
#pragma unroll
  for (int rg = 0; rg < 4; ++rg) {
    mu[rg] = sstat[quad * 4 + rg][0];
    rs[rg] = sstat[quad * 4 + rg][1];
  }
#pragma unroll
  for (int nt = 0; nt < 16; ++nt) {
    int c = wave * 256 + nt * 16 + lm;
    float g = gamma[c], be = beta[c];
#pragma unroll
    for (int rg = 0; rg < 4; ++rg) {
      int row = quad * 4 + rg;
      out[(size_t)(rowbase + row) * D + c] = (accv[nt][rg] - mu[rg]) * rs[rg] * g + be;
    }
  }
}

extern "C" void kernel_launch(void* const* d_in, const int* in_sizes, int n_in,
                              void* d_out, int out_size, void* d_ws, size_t ws_size,
                              hipStream_t stream) {
  const float* x     = (const float*)d_in[0];
  const float* Wp    = (const float*)d_in[1];
  const float* bp    = (const float*)d_in[2];
  const float* Wv    = (const float*)d_in[3];
  const float* bv    = (const float*)d_in[4];
  const float* Wi    = (const float*)d_in[5];
  const float* bi    = (const float*)d_in[6];
  const float* gamma = (const float*)d_in[7];
  const float* beta  = (const float*)d_in[8];
  float* out = (float*)d_out;

  unsigned short* Wpvt = (unsigned short*)d_ws;               // 32*2048 bf16
  unsigned short* Wit  = Wpvt + 32 * 2048;                    // 2048*160 bf16

  prep_wpv<<<(32 * 2048) / 256, 256, 0, stream>>>(Wp, Wv, Wpvt);
  prep_wi<<<(2048 * KPAD) / 256, 256, 0, stream>>>(Wi, Wit);

  int rows = in_sizes[0] / D;                                  // 32768
  gil_fused<<<rows / MTILE, THREADS, 0, stream>>>(x, bp, bv, bi, gamma, beta,
                                                  Wpvt, Wit, out);
}